// Round 4
// baseline (385.185 us; speedup 1.0000x reference)
//
#include <hip/hip_runtime.h>
#include <hip/hip_bf16.h>

// ---------------------------------------------------------------------------
// E8 RHT Linear:  y = SU * FHT( FHT(SV * x) @ W^T * Wscale ),  W from codebook
// M=8192 rows of x, K=4096, N=4096 output features.
// GEMM: 256x256 tile, BK=64, 8 waves, 8-phase counted-vmcnt schedule (T2-T5),
// 3-half-tile staging lead (vmcnt(6)/vmcnt(4), never 0 in steady state).
// ---------------------------------------------------------------------------

using short8 = __attribute__((ext_vector_type(8))) short;
using f32x4  = __attribute__((ext_vector_type(4))) float;

#define AS1 __attribute__((address_space(1)))
#define AS3 __attribute__((address_space(3)))

__device__ __forceinline__ unsigned short f2bf(float f) {
  unsigned int u = __float_as_uint(f);
  unsigned int r = (u + 0x7fffu + ((u >> 16) & 1u)) >> 16;
  return (unsigned short)r;
}

__device__ __forceinline__ void gload16(const void* g, void* l) {
  __builtin_amdgcn_global_load_lds((const AS1 void*)g, (AS3 void*)l, 16, 0, 0);
}

#define WAIT_VM6 asm volatile("s_waitcnt vmcnt(6)" ::: "memory")
#define WAIT_VM4 asm volatile("s_waitcnt vmcnt(4)" ::: "memory")
#define WAIT_VM0 asm volatile("s_waitcnt vmcnt(0)" ::: "memory")

// ---------------------------------------------------------------------------
// Kernel 1: A_rht[row][:] = unnormalized FHT_4096( x[row][:] * SV[:] ) as bf16
// ---------------------------------------------------------------------------
__global__ __launch_bounds__(256) void rht_in_kernel(const float* __restrict__ X,
                                                     const float* __restrict__ SV,
                                                     unsigned short* __restrict__ A) {
  __shared__ float tmp[4096];
  const int row = blockIdx.x;
  const int t = threadIdx.x;
  const size_t base = (size_t)row * 4096;
  float v[16];
#pragma unroll
  for (int j = 0; j < 16; ++j) {
    int c = j * 256 + t;
    v[j] = X[base + c] * SV[c];
  }
#pragma unroll
  for (int d = 1; d < 16; d <<= 1) {
#pragma unroll
    for (int j = 0; j < 16; ++j) {
      if ((j & d) == 0) {
        float a = v[j], b = v[j | d];
        v[j] = a + b;
        v[j | d] = a - b;
      }
    }
  }
  const int lane = t & 63;
#pragma unroll
  for (int d = 1; d < 64; d <<= 1) {
#pragma unroll
    for (int j = 0; j < 16; ++j) {
      float p = __shfl_xor(v[j], d, 64);
      v[j] = (lane & d) ? (p - v[j]) : (v[j] + p);
    }
  }
#pragma unroll
  for (int dd = 0; dd < 2; ++dd) {
    const int d = 64 << dd;
    if (dd) __syncthreads();
#pragma unroll
    for (int j = 0; j < 16; ++j) tmp[j * 256 + t] = v[j];
    __syncthreads();
#pragma unroll
    for (int j = 0; j < 16; ++j) {
      float p = tmp[j * 256 + (t ^ d)];
      v[j] = (t & d) ? (p - v[j]) : (v[j] + p);
    }
  }
#pragma unroll
  for (int j = 0; j < 16; ++j) A[base + j * 256 + t] = f2bf(v[j]);
}

// ---------------------------------------------------------------------------
// Kernel 2: decode W_rht (4096x4096) from codebook, bf16 row-major.
// ---------------------------------------------------------------------------
__global__ __launch_bounds__(256) void decode_w_kernel(const int* __restrict__ Q,
                                                       const float* __restrict__ cb,
                                                       unsigned short* __restrict__ W) {
  const int e = blockIdx.x * 256 + threadIdx.x;
  const int idx = Q[e];
  const float4* c = (const float4*)(cb + (size_t)idx * 8);
  float4 c0 = c[0], c1 = c[1];
  union { short8 v; unsigned short u[8]; } w;
  w.u[0] = f2bf(c0.x); w.u[1] = f2bf(c0.y); w.u[2] = f2bf(c0.z); w.u[3] = f2bf(c0.w);
  w.u[4] = f2bf(c1.x); w.u[5] = f2bf(c1.y); w.u[6] = f2bf(c1.z); w.u[7] = f2bf(c1.w);
  *(short8*)&W[(size_t)e * 8] = w.v;
}

// ---------------------------------------------------------------------------
// Kernel 3: C[8192][4096] f32 = A(bf16) @ B(bf16)^T  — 256^2 8-phase template
// LDS: sA/sB [buf][khalf][256 rows][32 k-elems]. 16B-chunk XOR swizzle within
// each 64B k-half row: LDS chunk = g ^ ((row>>1)&3) (verified 0 bank conflict).
// Inverse-swizzled global source, linear gload_lds dest (rule 21).
// Staging per tile: P1: A-h0+B-h0 (4 loads), P2: A-h1 (2), P3: B-h1 (2).
// Waits: vmcnt(6) @P2-end (guards half1 of current), vmcnt(4) @P4-end
// (guards half0 of next) — min 3-phase issue->need lead, covers L2 miss.
// ---------------------------------------------------------------------------
#define MFMA1(mi, ni, av, bv) \
  acc[mi][ni] = __builtin_amdgcn_mfma_f32_16x16x32_bf16(av, bv, acc[mi][ni], 0, 0, 0)

#define STAGE_A(BB, H, KTN) do {                                          \
  const unsigned short* gp_ = Ag + (KTN) * 64 + (H) * 32;                 \
  gload16(gp_, (unsigned short*)&sA[BB][H][0][0] + d0);                   \
  gload16(gp_ + (size_t)128 * 4096, (unsigned short*)&sA[BB][H][0][0] + d1); \
} while (0)

#define STAGE_B(BB, H, KTN) do {                                          \
  const unsigned short* gp_ = Bg + (KTN) * 64 + (H) * 32;                 \
  gload16(gp_, (unsigned short*)&sB[BB][H][0][0] + d0);                   \
  gload16(gp_ + (size_t)128 * 4096, (unsigned short*)&sB[BB][H][0][0] + d1); \
} while (0)

#define PH(BC, KS, MB, RDB, STG, WT) do {                                 \
  short8 a0_ = *(const short8*)&sA[BC][KS][wm + (MB + 0) * 16 + fr][qc];  \
  short8 a1_ = *(const short8*)&sA[BC][KS][wm + (MB + 1) * 16 + fr][qc];  \
  short8 a2_ = *(const short8*)&sA[BC][KS][wm + (MB + 2) * 16 + fr][qc];  \
  short8 a3_ = *(const short8*)&sA[BC][KS][wm + (MB + 3) * 16 + fr][qc];  \
  if (RDB) {                                                              \
    bf0 = *(const short8*)&sB[BC][KS][wn + 0 * 16 + fr][qc];              \
    bf1 = *(const short8*)&sB[BC][KS][wn + 1 * 16 + fr][qc];              \
    bf2 = *(const short8*)&sB[BC][KS][wn + 2 * 16 + fr][qc];              \
    bf3 = *(const short8*)&sB[BC][KS][wn + 3 * 16 + fr][qc];              \
  }                                                                       \
  STG;                                                                    \
  __builtin_amdgcn_s_barrier();                                           \
  asm volatile("s_waitcnt lgkmcnt(0)" ::: "memory");                      \
  __builtin_amdgcn_s_setprio(1);                                          \
  MFMA1(MB + 0, 0, a0_, bf0); MFMA1(MB + 0, 1, a0_, bf1);                 \
  MFMA1(MB + 0, 2, a0_, bf2); MFMA1(MB + 0, 3, a0_, bf3);                 \
  MFMA1(MB + 1, 0, a1_, bf0); MFMA1(MB + 1, 1, a1_, bf1);                 \
  MFMA1(MB + 1, 2, a1_, bf2); MFMA1(MB + 1, 3, a1_, bf3);                 \
  MFMA1(MB + 2, 0, a2_, bf0); MFMA1(MB + 2, 1, a2_, bf1);                 \
  MFMA1(MB + 2, 2, a2_, bf2); MFMA1(MB + 2, 3, a2_, bf3);                 \
  MFMA1(MB + 3, 0, a3_, bf0); MFMA1(MB + 3, 1, a3_, bf1);                 \
  MFMA1(MB + 3, 2, a3_, bf2); MFMA1(MB + 3, 3, a3_, bf3);                 \
  __builtin_amdgcn_s_setprio(0);                                          \
  WT;                                                                     \
  __builtin_amdgcn_s_barrier();                                           \
} while (0)

// DS: stage tile KTN into buf BN_.  LASTF: final K-tile (drain instead of count)
#define TILE(BC, BN_, KTN, DS, LASTF) do {                                \
  PH(BC, 0, 0, 1,                                                         \
     { if (DS) { STAGE_A(BN_, 0, KTN); STAGE_B(BN_, 0, KTN); } }, {});    \
  PH(BC, 0, 4, 0, { if (DS) { STAGE_A(BN_, 1, KTN); } },                  \
     { if (LASTF) { WAIT_VM0; } else { WAIT_VM6; } });                    \
  PH(BC, 1, 0, 1, { if (DS) { STAGE_B(BN_, 1, KTN); } }, {});             \
  PH(BC, 1, 4, 0, {}, { if (!(LASTF)) { WAIT_VM4; } });                   \
} while (0)

__global__ __launch_bounds__(512, 2) void gemm_bt_kernel(const unsigned short* __restrict__ A,
                                                         const unsigned short* __restrict__ B,
                                                         float* __restrict__ C) {
  __shared__ unsigned short sA[2][2][256][32];
  __shared__ unsigned short sB[2][2][256][32];

  const int bid = blockIdx.x;                    // 512 blocks = 32 tm x 16 tn
  const int swz = (bid & 7) * 64 + (bid >> 3);   // XCD swizzle (512 % 8 == 0)
  const int tm = swz >> 4;                       // 0..31
  const int tn = swz & 15;                       // 0..15

  const int t = threadIdx.x;
  const int lane = t & 63;
  const int w = t >> 6;
  const int wm = (w >> 2) * 128;                 // wave M offset (2 waves)
  const int wn = (w & 3) * 64;                   // wave N offset (4 waves)
  const int fr = lane & 15;
  // read-side swizzled k-chunk: global chunk g=lane>>4 lives at LDS chunk
  // g ^ ((row>>1)&3); row bits 1-2 == lane bits 1-2 (wm/wn/mb*16 touch bits>=4)
  const int qc = ((lane >> 4) ^ ((lane >> 1) & 3)) * 8;

  // staging: thread t covers LDS row sr=t>>2 (and sr+128), LDS chunk t&3;
  // source global chunk = (t&3) ^ swz(row), swz(row) = (row>>1)&3 = (t>>3)&3.
  const int sr = t >> 2;                         // 0..127
  const int sc = ((t & 3) ^ ((t >> 3) & 3)) * 8; // source k-chunk within half
  const unsigned short* Ag = A + (size_t)(tm * 256 + sr) * 4096 + sc;
  const unsigned short* Bg = B + (size_t)(tn * 256 + sr) * 4096 + sc;
  const int d0 = t * 8;                          // dest elem offset, load 0
  const int d1 = (512 + t) * 8;                  // dest elem offset, load 1

  f32x4 acc[8][4];
#pragma unroll
  for (int m = 0; m < 8; ++m)
#pragma unroll
    for (int n = 0; n < 4; ++n) {
      f32x4 z = {0.f, 0.f, 0.f, 0.f};
      acc[m][n] = z;
    }
  short8 bf0, bf1, bf2, bf3;

  // prologue: stage tile 0 (A0,B0,A1,B1 = 8 loads); need A0,B0 -> vmcnt(4)
  STAGE_A(0, 0, 0); STAGE_B(0, 0, 0); STAGE_A(0, 1, 0); STAGE_B(0, 1, 0);
  WAIT_VM4;
  __builtin_amdgcn_s_barrier();

  for (int k2 = 0; k2 < 31; ++k2) {
    TILE(0, 1, 2 * k2 + 1, 1, 0);
    TILE(1, 0, 2 * k2 + 2, 1, 0);
  }
  TILE(0, 1, 63, 1, 0);
  TILE(1, 0, 64, 0, 1);

  // epilogue: C/D layout col = lane&15, row = (lane>>4)*4 + j (nontemporal)
  const size_t crow0 = (size_t)tm * 256 + wm + (lane >> 4) * 4;
  const int ccol0 = tn * 256 + wn + fr;
#pragma unroll
  for (int mf = 0; mf < 8; ++mf)
#pragma unroll
    for (int j = 0; j < 4; ++j) {
      float* Cp = C + (crow0 + mf * 16 + j) * 4096 + ccol0;
#pragma unroll
      for (int nf = 0; nf < 4; ++nf)
        __builtin_nontemporal_store(acc[mf][nf][j], Cp + nf * 16);
    }
}

// ---------------------------------------------------------------------------
// Kernel 4: in-place FHT_4096 on each row of Y, then * SU * Wscale / 4096.
// ---------------------------------------------------------------------------
__global__ __launch_bounds__(256) void rht_out_kernel(float* __restrict__ Y,
                                                      const float* __restrict__ SU,
                                                      const float* __restrict__ Wscale) {
  __shared__ float tmp[4096];
  const int row = blockIdx.x;
  const int t = threadIdx.x;
  const size_t base = (size_t)row * 4096;
  float v[16];
#pragma unroll
  for (int j = 0; j < 16; ++j) v[j] = Y[base + j * 256 + t];
#pragma unroll
  for (int d = 1; d < 16; d <<= 1) {
#pragma unroll
    for (int j = 0; j < 16; ++j) {
      if ((j & d) == 0) {
        float a = v[j], b = v[j | d];
        v[j] = a + b;
        v[j | d] = a - b;
      }
    }
  }
  const int lane = t & 63;
#pragma unroll
  for (int d = 1; d < 64; d <<= 1) {
#pragma unroll
    for (int j = 0; j < 16; ++j) {
      float p = __shfl_xor(v[j], d, 64);
      v[j] = (lane & d) ? (p - v[j]) : (v[j] + p);
    }
  }
#pragma unroll
  for (int dd = 0; dd < 2; ++dd) {
    const int d = 64 << dd;
    if (dd) __syncthreads();
#pragma unroll
    for (int j = 0; j < 16; ++j) tmp[j * 256 + t] = v[j];
    __syncthreads();
#pragma unroll
    for (int j = 0; j < 16; ++j) {
      float p = tmp[j * 256 + (t ^ d)];
      v[j] = (t & d) ? (p - v[j]) : (v[j] + p);
    }
  }
  const float ws = Wscale[0] * (1.0f / 4096.0f);
#pragma unroll
  for (int j = 0; j < 16; ++j) {
    int c = j * 256 + t;
    __builtin_nontemporal_store(v[j] * SU[c] * ws, &Y[base + c]);
  }
}

// ---------------------------------------------------------------------------
extern "C" void kernel_launch(void* const* d_in, const int* in_sizes, int n_in,
                              void* d_out, int out_size, void* d_ws, size_t ws_size,
                              hipStream_t stream) {
  const float* x      = (const float*)d_in[0];
  const int*   Qidxs  = (const int*)d_in[1];
  const float* SU     = (const float*)d_in[2];
  const float* SV     = (const float*)d_in[3];
  const float* Wscale = (const float*)d_in[4];
  const float* cb     = (const float*)d_in[5];
  float* out = (float*)d_out;

  unsigned short* Arht = (unsigned short*)d_ws;
  unsigned short* W    = (unsigned short*)((char*)d_ws + (size_t)8192 * 4096 * 2);

  rht_in_kernel<<<8192, 256, 0, stream>>>(x, SV, Arht);
  decode_w_kernel<<<(4096 * 512) / 256, 256, 0, stream>>>(Qidxs, cb, W);
  gemm_bt_kernel<<<512, 512, 0, stream>>>(Arht, W, out);
  rht_out_kernel<<<8192, 256, 0, stream>>>(out, SU, Wscale);
}

// Round 5
// 356.310 us; speedup vs baseline: 1.0810x; 1.0810x over previous
//
#include <hip/hip_runtime.h>
#include <hip/hip_bf16.h>

// ---------------------------------------------------------------------------
// E8 RHT Linear:  y = SU * FHT( FHT(SV * x) @ W^T * Wscale ),  W from codebook
// M=8192 rows of x, K=4096, N=4096 output features.
// GEMM: 256x256 tile, BK=64, 8 waves, 8-phase counted-vmcnt schedule with
// one-phase-ahead ds_read prefetch (frag register double-buffering).
// ---------------------------------------------------------------------------

using short8 = __attribute__((ext_vector_type(8))) short;
using f32x4  = __attribute__((ext_vector_type(4))) float;

#define AS1 __attribute__((address_space(1)))
#define AS3 __attribute__((address_space(3)))

__device__ __forceinline__ unsigned short f2bf(float f) {
  unsigned int u = __float_as_uint(f);
  unsigned int r = (u + 0x7fffu + ((u >> 16) & 1u)) >> 16;
  return (unsigned short)r;
}

__device__ __forceinline__ void gload16(const void* g, void* l) {
  __builtin_amdgcn_global_load_lds((const AS1 void*)g, (AS3 void*)l, 16, 0, 0);
}

#define WAIT_VM4 asm volatile("s_waitcnt vmcnt(4)" ::: "memory")
#define WAIT_VM0 asm volatile("s_waitcnt vmcnt(0)" ::: "memory")
#define LGKM0    asm volatile("s_waitcnt lgkmcnt(0)" ::: "memory")
#define SB       __builtin_amdgcn_sched_barrier(0)
#define BAR      __builtin_amdgcn_s_barrier()
#define PRIO1    __builtin_amdgcn_s_setprio(1)
#define PRIO0    __builtin_amdgcn_s_setprio(0)

// ---------------------------------------------------------------------------
// Kernel 1: A_rht[row][:] = unnormalized FHT_4096( x[row][:] * SV[:] ) as bf16
// ---------------------------------------------------------------------------
__global__ __launch_bounds__(256) void rht_in_kernel(const float* __restrict__ X,
                                                     const float* __restrict__ SV,
                                                     unsigned short* __restrict__ A) {
  __shared__ float tmp[4096];
  const int row = blockIdx.x;
  const int t = threadIdx.x;
  const size_t base = (size_t)row * 4096;
  float v[16];
#pragma unroll
  for (int j = 0; j < 16; ++j) {
    int c = j * 256 + t;
    v[j] = X[base + c] * SV[c];
  }
#pragma unroll
  for (int d = 1; d < 16; d <<= 1) {
#pragma unroll
    for (int j = 0; j < 16; ++j) {
      if ((j & d) == 0) {
        float a = v[j], b = v[j | d];
        v[j] = a + b;
        v[j | d] = a - b;
      }
    }
  }
  const int lane = t & 63;
#pragma unroll
  for (int d = 1; d < 64; d <<= 1) {
#pragma unroll
    for (int j = 0; j < 16; ++j) {
      float p = __shfl_xor(v[j], d, 64);
      v[j] = (lane & d) ? (p - v[j]) : (v[j] + p);
    }
  }
#pragma unroll
  for (int dd = 0; dd < 2; ++dd) {
    const int d = 64 << dd;
    if (dd) __syncthreads();
#pragma unroll
    for (int j = 0; j < 16; ++j) tmp[j * 256 + t] = v[j];
    __syncthreads();
#pragma unroll
    for (int j = 0; j < 16; ++j) {
      float p = tmp[j * 256 + (t ^ d)];
      v[j] = (t & d) ? (p - v[j]) : (v[j] + p);
    }
  }
#pragma unroll
  for (int j = 0; j < 16; ++j) A[base + j * 256 + t] = f2bf(v[j]);
}

// ---------------------------------------------------------------------------
// Kernel 2: decode W_rht (4096x4096) from codebook, bf16 row-major.
// ---------------------------------------------------------------------------
__global__ __launch_bounds__(256) void decode_w_kernel(const int* __restrict__ Q,
                                                       const float* __restrict__ cb,
                                                       unsigned short* __restrict__ W) {
  const int e = blockIdx.x * 256 + threadIdx.x;
  const int idx = Q[e];
  const float4* c = (const float4*)(cb + (size_t)idx * 8);
  float4 c0 = c[0], c1 = c[1];
  union { short8 v; unsigned short u[8]; } w;
  w.u[0] = f2bf(c0.x); w.u[1] = f2bf(c0.y); w.u[2] = f2bf(c0.z); w.u[3] = f2bf(c0.w);
  w.u[4] = f2bf(c1.x); w.u[5] = f2bf(c1.y); w.u[6] = f2bf(c1.z); w.u[7] = f2bf(c1.w);
  *(short8*)&W[(size_t)e * 8] = w.v;
}

// ---------------------------------------------------------------------------
// Kernel 3: C = A @ B^T — 256^2 8-phase template + 1-phase-ahead ds prefetch.
// LDS: sA/sB [buf][khalf][256][32], 16B-chunk XOR swizzle g^((row>>1)&3)
// (0 bank conflicts, verified r3). Staging: A0@P1, B0@P2, A1@P3, B1@P4.
// Waits: vmcnt(4) inside P2 (guards khalf1 BEFORE its prefetch reads),
// vmcnt(4) at P4-end (guards next tile's khalf0). Never 0 until last tile.
// Frag double-buffer: aS0 (P1/P3 compute), aS1 (P2/P4), bA=khalf0, bB=khalf1.
// ---------------------------------------------------------------------------
#define MFMA1(mi, ni, av, bv) \
  acc[mi][ni] = __builtin_amdgcn_mfma_f32_16x16x32_bf16(av, bv, acc[mi][ni], 0, 0, 0)

#define MFMA16(MB, a0_, a1_, a2_, a3_, bx0, bx1, bx2, bx3) do {           \
  MFMA1(MB + 0, 0, a0_, bx0); MFMA1(MB + 0, 1, a0_, bx1);                 \
  MFMA1(MB + 0, 2, a0_, bx2); MFMA1(MB + 0, 3, a0_, bx3);                 \
  MFMA1(MB + 1, 0, a1_, bx0); MFMA1(MB + 1, 1, a1_, bx1);                 \
  MFMA1(MB + 1, 2, a1_, bx2); MFMA1(MB + 1, 3, a1_, bx3);                 \
  MFMA1(MB + 2, 0, a2_, bx0); MFMA1(MB + 2, 1, a2_, bx1);                 \
  MFMA1(MB + 2, 2, a2_, bx2); MFMA1(MB + 2, 3, a2_, bx3);                 \
  MFMA1(MB + 3, 0, a3_, bx0); MFMA1(MB + 3, 1, a3_, bx1);                 \
  MFMA1(MB + 3, 2, a3_, bx2); MFMA1(MB + 3, 3, a3_, bx3);                 \
} while (0)

#define RD_A4(r0, r1, r2, r3, BC, KS, MB) do {                            \
  r0 = *(const short8*)&sA[BC][KS][wm + (MB + 0) * 16 + fr][qc];          \
  r1 = *(const short8*)&sA[BC][KS][wm + (MB + 1) * 16 + fr][qc];          \
  r2 = *(const short8*)&sA[BC][KS][wm + (MB + 2) * 16 + fr][qc];          \
  r3 = *(const short8*)&sA[BC][KS][wm + (MB + 3) * 16 + fr][qc];          \
} while (0)

#define RD_B4(r0, r1, r2, r3, BC, KS) do {                                \
  r0 = *(const short8*)&sB[BC][KS][wn + 0 * 16 + fr][qc];                 \
  r1 = *(const short8*)&sB[BC][KS][wn + 1 * 16 + fr][qc];                 \
  r2 = *(const short8*)&sB[BC][KS][wn + 2 * 16 + fr][qc];                 \
  r3 = *(const short8*)&sB[BC][KS][wn + 3 * 16 + fr][qc];                 \
} while (0)

#define STAGE_A(BB, H, KTN) do {                                          \
  const unsigned short* gp_ = Ag + (KTN) * 64 + (H) * 32;                 \
  gload16(gp_, (unsigned short*)&sA[BB][H][0][0] + d0);                   \
  gload16(gp_ + (size_t)128 * 4096, (unsigned short*)&sA[BB][H][0][0] + d1); \
} while (0)

#define STAGE_B(BB, H, KTN) do {                                          \
  const unsigned short* gp_ = Bg + (KTN) * 64 + (H) * 32;                 \
  gload16(gp_, (unsigned short*)&sB[BB][H][0][0] + d0);                   \
  gload16(gp_ + (size_t)128 * 4096, (unsigned short*)&sB[BB][H][0][0] + d1); \
} while (0)

#define TILE(BC, BN_, KTN, DS, LASTF) do {                                \
  /* P1: top-read own frags (khalf0), prefetch aS1 during MFMA */         \
  RD_A4(aS0_0, aS0_1, aS0_2, aS0_3, BC, 0, 0);                            \
  RD_B4(bA_0, bA_1, bA_2, bA_3, BC, 0);                                   \
  if (DS) { STAGE_A(BN_, 0, KTN); }                                       \
  BAR; LGKM0; SB;                                                         \
  RD_A4(aS1_0, aS1_1, aS1_2, aS1_3, BC, 0, 4); SB;                        \
  PRIO1; MFMA16(0, aS0_0, aS0_1, aS0_2, aS0_3, bA_0, bA_1, bA_2, bA_3);   \
  PRIO0; BAR;                                                             \
  /* P2: vmcnt guards khalf1, then prefetch khalf1 frags */               \
  if (DS) { STAGE_B(BN_, 0, KTN); }                                       \
  BAR; LGKM0; SB;                                                         \
  if (LASTF) { WAIT_VM0; } else { WAIT_VM4; }                             \
  RD_A4(aS0_0, aS0_1, aS0_2, aS0_3, BC, 1, 0);                            \
  RD_B4(bB_0, bB_1, bB_2, bB_3, BC, 1); SB;                               \
  PRIO1; MFMA16(4, aS1_0, aS1_1, aS1_2, aS1_3, bA_0, bA_1, bA_2, bA_3);   \
  PRIO0; BAR;                                                             \
  /* P3: prefetch aS1 (khalf1 mb4-7) */                                   \
  if (DS) { STAGE_A(BN_, 1, KTN); }                                       \
  BAR; LGKM0; SB;                                                         \
  RD_A4(aS1_0, aS1_1, aS1_2, aS1_3, BC, 1, 4); SB;                        \
  PRIO1; MFMA16(0, aS0_0, aS0_1, aS0_2, aS0_3, bB_0, bB_1, bB_2, bB_3);   \
  PRIO0; BAR;                                                             \
  /* P4: no prefetch (next tile P1 reads after its own guard) */          \
  if (DS) { STAGE_B(BN_, 1, KTN); }                                       \
  BAR; LGKM0; SB;                                                         \
  PRIO1; MFMA16(4, aS1_0, aS1_1, aS1_2, aS1_3, bB_0, bB_1, bB_2, bB_3);   \
  PRIO0;                                                                  \
  if (!(LASTF)) { WAIT_VM4; }                                             \
  BAR;                                                                    \
} while (0)

__global__ __launch_bounds__(512, 2) void gemm_bt_kernel(const unsigned short* __restrict__ A,
                                                         const unsigned short* __restrict__ B,
                                                         float* __restrict__ C) {
  __shared__ unsigned short sA[2][2][256][32];
  __shared__ unsigned short sB[2][2][256][32];

  const int bid = blockIdx.x;                    // 512 blocks = 32 tm x 16 tn
  const int swz = (bid & 7) * 64 + (bid >> 3);   // XCD swizzle (512 % 8 == 0)
  const int tm = swz >> 4;                       // 0..31
  const int tn = swz & 15;                       // 0..15

  const int t = threadIdx.x;
  const int lane = t & 63;
  const int w = t >> 6;
  const int wm = (w >> 2) * 128;                 // wave M offset (2 waves)
  const int wn = (w & 3) * 64;                   // wave N offset (4 waves)
  const int fr = lane & 15;
  // read-side swizzled k-chunk: global chunk g=lane>>4 lives at LDS chunk
  // g ^ ((row>>1)&3); row bits 1-2 == lane bits 1-2 (wm/wn/mb*16 touch bits>=4)
  const int qc = ((lane >> 4) ^ ((lane >> 1) & 3)) * 8;

  // staging: thread t covers LDS row sr=t>>2 (and sr+128), LDS chunk t&3;
  // source global chunk = (t&3) ^ swz(row), swz(row) = (row>>1)&3 = (t>>3)&3.
  const int sr = t >> 2;                         // 0..127
  const int sc = ((t & 3) ^ ((t >> 3) & 3)) * 8; // source k-chunk within half
  const unsigned short* Ag = A + (size_t)(tm * 256 + sr) * 4096 + sc;
  const unsigned short* Bg = B + (size_t)(tn * 256 + sr) * 4096 + sc;
  const int d0 = t * 8;                          // dest elem offset, load 0
  const int d1 = (512 + t) * 8;                  // dest elem offset, load 1

  f32x4 acc[8][4];
#pragma unroll
  for (int m = 0; m < 8; ++m)
#pragma unroll
    for (int n = 0; n < 4; ++n) {
      f32x4 z = {0.f, 0.f, 0.f, 0.f};
      acc[m][n] = z;
    }
  short8 aS0_0, aS0_1, aS0_2, aS0_3;
  short8 aS1_0, aS1_1, aS1_2, aS1_3;
  short8 bA_0, bA_1, bA_2, bA_3;
  short8 bB_0, bB_1, bB_2, bB_3;

  // prologue: stage tile 0 (A0,B0,A1,B1 = 8 loads); need A0,B0 -> vmcnt(4)
  STAGE_A(0, 0, 0); STAGE_B(0, 0, 0); STAGE_A(0, 1, 0); STAGE_B(0, 1, 0);
  WAIT_VM4;
  BAR;

  for (int k2 = 0; k2 < 31; ++k2) {
    TILE(0, 1, 2 * k2 + 1, 1, 0);
    TILE(1, 0, 2 * k2 + 2, 1, 0);
  }
  TILE(0, 1, 63, 1, 0);
  TILE(1, 0, 64, 0, 1);

  // epilogue: C/D layout col = lane&15, row = (lane>>4)*4 + j
  const size_t crow0 = (size_t)tm * 256 + wm + (lane >> 4) * 4;
  const int ccol0 = tn * 256 + wn + fr;
#pragma unroll
  for (int mf = 0; mf < 8; ++mf)
#pragma unroll
    for (int j = 0; j < 4; ++j) {
      float* Cp = C + (crow0 + mf * 16 + j) * 4096 + ccol0;
#pragma unroll
      for (int nf = 0; nf < 4; ++nf) Cp[nf * 16] = acc[mf][nf][j];
    }
}

// ---------------------------------------------------------------------------
// Kernel 4: in-place FHT_4096 on each row of Y, then * SU * Wscale / 4096.
// ---------------------------------------------------------------------------
__global__ __launch_bounds__(256) void rht_out_kernel(float* __restrict__ Y,
                                                      const float* __restrict__ SU,
                                                      const float* __restrict__ Wscale) {
  __shared__ float tmp[4096];
  const int row = blockIdx.x;
  const int t = threadIdx.x;
  const size_t base = (size_t)row * 4096;
  float v[16];
#pragma unroll
  for (int j = 0; j < 16; ++j) v[j] = Y[base + j * 256 + t];
#pragma unroll
  for (int d = 1; d < 16; d <<= 1) {
#pragma unroll
    for (int j = 0; j < 16; ++j) {
      if ((j & d) == 0) {
        float a = v[j], b = v[j | d];
        v[j] = a + b;
        v[j | d] = a - b;
      }
    }
  }
  const int lane = t & 63;
#pragma unroll
  for (int d = 1; d < 64; d <<= 1) {
#pragma unroll
    for (int j = 0; j < 16; ++j) {
      float p = __shfl_xor(v[j], d, 64);
      v[j] = (lane & d) ? (p - v[j]) : (v[j] + p);
    }
  }
#pragma unroll
  for (int dd = 0; dd < 2; ++dd) {
    const int d = 64 << dd;
    if (dd) __syncthreads();
#pragma unroll
    for (int j = 0; j < 16; ++j) tmp[j * 256 + t] = v[j];
    __syncthreads();
#pragma unroll
    for (int j = 0; j < 16; ++j) {
      float p = tmp[j * 256 + (t ^ d)];
      v[j] = (t & d) ? (p - v[j]) : (v[j] + p);
    }
  }
  const float ws = Wscale[0] * (1.0f / 4096.0f);
#pragma unroll
  for (int j = 0; j < 16; ++j) {
    int c = j * 256 + t;
    Y[base + c] = v[j] * SU[c] * ws;
  }
}

// ---------------------------------------------------------------------------
extern "C" void kernel_launch(void* const* d_in, const int* in_sizes, int n_in,
                              void* d_out, int out_size, void* d_ws, size_t ws_size,
                              hipStream_t stream) {
  const float* x      = (const float*)d_in[0];
  const int*   Qidxs  = (const int*)d_in[1];
  const float* SU     = (const float*)d_in[2];
  const float* SV     = (const float*)d_in[3];
  const float* Wscale = (const float*)d_in[4];
  const float* cb     = (const float*)d_in[5];
  float* out = (float*)d_out;

  unsigned short* Arht = (unsigned short*)d_ws;
  unsigned short* W    = (unsigned short*)((char*)d_ws + (size_t)8192 * 4096 * 2);

  rht_in_kernel<<<8192, 256, 0, stream>>>(x, SV, Arht);
  decode_w_kernel<<<(4096 * 512) / 256, 256, 0, stream>>>(Qidxs, cb, W);
  gemm_bt_kernel<<<512, 512, 0, stream>>>(Arht, W, out);
  rht_out_kernel<<<8192, 256, 0, stream>>>(out, SU, Wscale);
}

// Round 6
// 349.184 us; speedup vs baseline: 1.1031x; 1.0204x over previous
//
#include <hip/hip_runtime.h>
#include <hip/hip_bf16.h>

// ---------------------------------------------------------------------------
// E8 RHT Linear:  y = SU * FHT( FHT(SV * x) @ W^T * Wscale ),  W from codebook
// M=8192 rows of x, K=4096, N=4096 output features.
// GEMM: 256x256 tile, BK=64, 8 waves, 8-phase counted-vmcnt schedule (r5,
// frozen). C stored as bf16 in workspace when ws_size allows (160 MB layout).
// ---------------------------------------------------------------------------

using short8 = __attribute__((ext_vector_type(8))) short;
using f32x4  = __attribute__((ext_vector_type(4))) float;

#define AS1 __attribute__((address_space(1)))
#define AS3 __attribute__((address_space(3)))

__device__ __forceinline__ unsigned short f2bf(float f) {
  unsigned int u = __float_as_uint(f);
  unsigned int r = (u + 0x7fffu + ((u >> 16) & 1u)) >> 16;
  return (unsigned short)r;
}

__device__ __forceinline__ float bf2f(unsigned short u) {
  return __uint_as_float((unsigned int)u << 16);
}

__device__ __forceinline__ void gload16(const void* g, void* l) {
  __builtin_amdgcn_global_load_lds((const AS1 void*)g, (AS3 void*)l, 16, 0, 0);
}

#define WAIT_VM4 asm volatile("s_waitcnt vmcnt(4)" ::: "memory")
#define WAIT_VM0 asm volatile("s_waitcnt vmcnt(0)" ::: "memory")
#define LGKM0    asm volatile("s_waitcnt lgkmcnt(0)" ::: "memory")
#define SB       __builtin_amdgcn_sched_barrier(0)
#define BAR      __builtin_amdgcn_s_barrier()
#define PRIO1    __builtin_amdgcn_s_setprio(1)
#define PRIO0    __builtin_amdgcn_s_setprio(0)

// ---------------------------------------------------------------------------
// FHT core over element map e = t*16 + j (j=reg 0..15, t=thread 0..255):
//   H16 over j-bits (elem dist 1,2,4,8), H64 over t-bits0-5 via shfl
//   (dist 16..512), H4 over t-bits6-7 via LDS (dist 1024,2048).
// ---------------------------------------------------------------------------
#define FHT_BODY(v, tmp, t, lane)                                         \
  _Pragma("unroll")                                                       \
  for (int d = 1; d < 16; d <<= 1) {                                      \
    _Pragma("unroll")                                                     \
    for (int j = 0; j < 16; ++j) {                                        \
      if ((j & d) == 0) {                                                 \
        float a_ = v[j], b_ = v[j | d];                                   \
        v[j] = a_ + b_;                                                   \
        v[j | d] = a_ - b_;                                               \
      }                                                                   \
    }                                                                     \
  }                                                                       \
  _Pragma("unroll")                                                       \
  for (int d = 1; d < 64; d <<= 1) {                                      \
    _Pragma("unroll")                                                     \
    for (int j = 0; j < 16; ++j) {                                        \
      float p_ = __shfl_xor(v[j], d, 64);                                 \
      v[j] = (lane & d) ? (p_ - v[j]) : (v[j] + p_);                      \
    }                                                                     \
  }                                                                       \
  _Pragma("unroll")                                                       \
  for (int dd = 0; dd < 2; ++dd) {                                        \
    const int d = 64 << dd;                                               \
    if (dd) __syncthreads();                                              \
    _Pragma("unroll")                                                     \
    for (int j = 0; j < 16; ++j) tmp[j * 256 + t] = v[j];                 \
    __syncthreads();                                                      \
    _Pragma("unroll")                                                     \
    for (int j = 0; j < 16; ++j) {                                        \
      float p_ = tmp[j * 256 + (t ^ d)];                                  \
      v[j] = (t & d) ? (p_ - v[j]) : (v[j] + p_);                         \
    }                                                                     \
  }

// ---------------------------------------------------------------------------
// Kernel 1: A_rht[row][:] = unnormalized FHT_4096( x[row][:] * SV[:] ) as bf16
// float4 loads (16B/lane), short8 stores (2x16B/lane).
// ---------------------------------------------------------------------------
__global__ __launch_bounds__(256) void rht_in_kernel(const float* __restrict__ X,
                                                     const float* __restrict__ SV,
                                                     unsigned short* __restrict__ A) {
  __shared__ float tmp[4096];
  const int row = blockIdx.x;
  const int t = threadIdx.x;
  const int lane = t & 63;
  const size_t base = (size_t)row * 4096;
  const float4* X4 = (const float4*)(X + base);
  const float4* SV4 = (const float4*)SV;
  float v[16];
#pragma unroll
  for (int q = 0; q < 4; ++q) {
    float4 xv = X4[t * 4 + q];
    float4 sv = SV4[t * 4 + q];
    v[q * 4 + 0] = xv.x * sv.x;
    v[q * 4 + 1] = xv.y * sv.y;
    v[q * 4 + 2] = xv.z * sv.z;
    v[q * 4 + 3] = xv.w * sv.w;
  }
  FHT_BODY(v, tmp, t, lane)
  union { short8 s; unsigned short u[8]; } lo, hi;
#pragma unroll
  for (int j = 0; j < 8; ++j) { lo.u[j] = f2bf(v[j]); hi.u[j] = f2bf(v[8 + j]); }
  short8* Ap = (short8*)(A + base + t * 16);
  Ap[0] = lo.s;
  Ap[1] = hi.s;
}

// ---------------------------------------------------------------------------
// Kernel 2: decode W_rht (4096x4096) from codebook, bf16 row-major.
// ---------------------------------------------------------------------------
__global__ __launch_bounds__(256) void decode_w_kernel(const int* __restrict__ Q,
                                                       const float* __restrict__ cb,
                                                       unsigned short* __restrict__ W) {
  const int e = blockIdx.x * 256 + threadIdx.x;
  const int idx = Q[e];
  const float4* c = (const float4*)(cb + (size_t)idx * 8);
  float4 c0 = c[0], c1 = c[1];
  union { short8 v; unsigned short u[8]; } w;
  w.u[0] = f2bf(c0.x); w.u[1] = f2bf(c0.y); w.u[2] = f2bf(c0.z); w.u[3] = f2bf(c0.w);
  w.u[4] = f2bf(c1.x); w.u[5] = f2bf(c1.y); w.u[6] = f2bf(c1.z); w.u[7] = f2bf(c1.w);
  *(short8*)&W[(size_t)e * 8] = w.v;
}

// ---------------------------------------------------------------------------
// Kernel 3: C = A @ B^T — 256^2 8-phase template + 1-phase-ahead ds prefetch.
// K-loop identical to round 5 (tied-best, 0 bank conflicts). Epilogue is
// templated: CM=0 -> f32 C, CM=1 -> bf16 C into workspace.
// ---------------------------------------------------------------------------
#define MFMA1(mi, ni, av, bv) \
  acc[mi][ni] = __builtin_amdgcn_mfma_f32_16x16x32_bf16(av, bv, acc[mi][ni], 0, 0, 0)

#define MFMA16(MB, a0_, a1_, a2_, a3_, bx0, bx1, bx2, bx3) do {           \
  MFMA1(MB + 0, 0, a0_, bx0); MFMA1(MB + 0, 1, a0_, bx1);                 \
  MFMA1(MB + 0, 2, a0_, bx2); MFMA1(MB + 0, 3, a0_, bx3);                 \
  MFMA1(MB + 1, 0, a1_, bx0); MFMA1(MB + 1, 1, a1_, bx1);                 \
  MFMA1(MB + 1, 2, a1_, bx2); MFMA1(MB + 1, 3, a1_, bx3);                 \
  MFMA1(MB + 2, 0, a2_, bx0); MFMA1(MB + 2, 1, a2_, bx1);                 \
  MFMA1(MB + 2, 2, a2_, bx2); MFMA1(MB + 2, 3, a2_, bx3);                 \
  MFMA1(MB + 3, 0, a3_, bx0); MFMA1(MB + 3, 1, a3_, bx1);                 \
  MFMA1(MB + 3, 2, a3_, bx2); MFMA1(MB + 3, 3, a3_, bx3);                 \
} while (0)

#define RD_A4(r0, r1, r2, r3, BC, KS, MB) do {                            \
  r0 = *(const short8*)&sA[BC][KS][wm + (MB + 0) * 16 + fr][qc];          \
  r1 = *(const short8*)&sA[BC][KS][wm + (MB + 1) * 16 + fr][qc];          \
  r2 = *(const short8*)&sA[BC][KS][wm + (MB + 2) * 16 + fr][qc];          \
  r3 = *(const short8*)&sA[BC][KS][wm + (MB + 3) * 16 + fr][qc];          \
} while (0)

#define RD_B4(r0, r1, r2, r3, BC, KS) do {                                \
  r0 = *(const short8*)&sB[BC][KS][wn + 0 * 16 + fr][qc];                 \
  r1 = *(const short8*)&sB[BC][KS][wn + 1 * 16 + fr][qc];                 \
  r2 = *(const short8*)&sB[BC][KS][wn + 2 * 16 + fr][qc];                 \
  r3 = *(const short8*)&sB[BC][KS][wn + 3 * 16 + fr][qc];                 \
} while (0)

#define STAGE_A(BB, H, KTN) do {                                          \
  const unsigned short* gp_ = Ag + (KTN) * 64 + (H) * 32;                 \
  gload16(gp_, (unsigned short*)&sA[BB][H][0][0] + d0);                   \
  gload16(gp_ + (size_t)128 * 4096, (unsigned short*)&sA[BB][H][0][0] + d1); \
} while (0)

#define STAGE_B(BB, H, KTN) do {                                          \
  const unsigned short* gp_ = Bg + (KTN) * 64 + (H) * 32;                 \
  gload16(gp_, (unsigned short*)&sB[BB][H][0][0] + d0);                   \
  gload16(gp_ + (size_t)128 * 4096, (unsigned short*)&sB[BB][H][0][0] + d1); \
} while (0)

#define TILE(BC, BN_, KTN, DS, LASTF) do {                                \
  /* P1: top-read own frags (khalf0), prefetch aS1 during MFMA */         \
  RD_A4(aS0_0, aS0_1, aS0_2, aS0_3, BC, 0, 0);                            \
  RD_B4(bA_0, bA_1, bA_2, bA_3, BC, 0);                                   \
  if (DS) { STAGE_A(BN_, 0, KTN); }                                       \
  BAR; LGKM0; SB;                                                         \
  RD_A4(aS1_0, aS1_1, aS1_2, aS1_3, BC, 0, 4); SB;                        \
  PRIO1; MFMA16(0, aS0_0, aS0_1, aS0_2, aS0_3, bA_0, bA_1, bA_2, bA_3);   \
  PRIO0; BAR;                                                             \
  /* P2: vmcnt guards khalf1, then prefetch khalf1 frags */               \
  if (DS) { STAGE_B(BN_, 0, KTN); }                                       \
  BAR; LGKM0; SB;                                                         \
  if (LASTF) { WAIT_VM0; } else { WAIT_VM4; }                             \
  RD_A4(aS0_0, aS0_1, aS0_2, aS0_3, BC, 1, 0);                            \
  RD_B4(bB_0, bB_1, bB_2, bB_3, BC, 1); SB;                               \
  PRIO1; MFMA16(4, aS1_0, aS1_1, aS1_2, aS1_3, bA_0, bA_1, bA_2, bA_3);   \
  PRIO0; BAR;                                                             \
  /* P3: prefetch aS1 (khalf1 mb4-7) */                                   \
  if (DS) { STAGE_A(BN_, 1, KTN); }                                       \
  BAR; LGKM0; SB;                                                         \
  RD_A4(aS1_0, aS1_1, aS1_2, aS1_3, BC, 1, 4); SB;                        \
  PRIO1; MFMA16(0, aS0_0, aS0_1, aS0_2, aS0_3, bB_0, bB_1, bB_2, bB_3);   \
  PRIO0; BAR;                                                             \
  /* P4: no prefetch (next tile P1 reads after its own guard) */          \
  if (DS) { STAGE_B(BN_, 1, KTN); }                                       \
  BAR; LGKM0; SB;                                                         \
  PRIO1; MFMA16(4, aS1_0, aS1_1, aS1_2, aS1_3, bB_0, bB_1, bB_2, bB_3);   \
  PRIO0;                                                                  \
  if (!(LASTF)) { WAIT_VM4; }                                             \
  BAR;                                                                    \
} while (0)

template <int CM>
__global__ __launch_bounds__(512, 2) void gemm_bt_kernel(const unsigned short* __restrict__ A,
                                                         const unsigned short* __restrict__ B,
                                                         float* __restrict__ C,
                                                         unsigned short* __restrict__ Cb) {
  __shared__ unsigned short sA[2][2][256][32];
  __shared__ unsigned short sB[2][2][256][32];

  const int bid = blockIdx.x;                    // 512 blocks = 32 tm x 16 tn
  const int swz = (bid & 7) * 64 + (bid >> 3);   // XCD swizzle (512 % 8 == 0)
  const int tm = swz >> 4;                       // 0..31
  const int tn = swz & 15;                       // 0..15

  const int t = threadIdx.x;
  const int lane = t & 63;
  const int w = t >> 6;
  const int wm = (w >> 2) * 128;                 // wave M offset (2 waves)
  const int wn = (w & 3) * 64;                   // wave N offset (4 waves)
  const int fr = lane & 15;
  // read-side swizzled k-chunk: global chunk g=lane>>4 lives at LDS chunk
  // g ^ ((row>>1)&3); row bits 1-2 == lane bits 1-2 (wm/wn/mb*16 touch bits>=4)
  const int qc = ((lane >> 4) ^ ((lane >> 1) & 3)) * 8;

  // staging: thread t covers LDS row sr=t>>2 (and sr+128), LDS chunk t&3;
  // source global chunk = (t&3) ^ swz(row), swz(row) = (row>>1)&3 = (t>>3)&3.
  const int sr = t >> 2;                         // 0..127
  const int sc = ((t & 3) ^ ((t >> 3) & 3)) * 8; // source k-chunk within half
  const unsigned short* Ag = A + (size_t)(tm * 256 + sr) * 4096 + sc;
  const unsigned short* Bg = B + (size_t)(tn * 256 + sr) * 4096 + sc;
  const int d0 = t * 8;                          // dest elem offset, load 0
  const int d1 = (512 + t) * 8;                  // dest elem offset, load 1

  f32x4 acc[8][4];
#pragma unroll
  for (int m = 0; m < 8; ++m)
#pragma unroll
    for (int n = 0; n < 4; ++n) {
      f32x4 z = {0.f, 0.f, 0.f, 0.f};
      acc[m][n] = z;
    }
  short8 aS0_0, aS0_1, aS0_2, aS0_3;
  short8 aS1_0, aS1_1, aS1_2, aS1_3;
  short8 bA_0, bA_1, bA_2, bA_3;
  short8 bB_0, bB_1, bB_2, bB_3;

  // prologue: stage tile 0 (A0,B0,A1,B1 = 8 loads); need A0,B0 -> vmcnt(4)
  STAGE_A(0, 0, 0); STAGE_B(0, 0, 0); STAGE_A(0, 1, 0); STAGE_B(0, 1, 0);
  WAIT_VM4;
  BAR;

  for (int k2 = 0; k2 < 31; ++k2) {
    TILE(0, 1, 2 * k2 + 1, 1, 0);
    TILE(1, 0, 2 * k2 + 2, 1, 0);
  }
  TILE(0, 1, 63, 1, 0);
  TILE(1, 0, 64, 0, 1);

  // epilogue: C/D layout col = lane&15, row = (lane>>4)*4 + j
  const size_t crow0 = (size_t)tm * 256 + wm + (lane >> 4) * 4;
  const int ccol0 = tn * 256 + wn + fr;
#pragma unroll
  for (int mf = 0; mf < 8; ++mf)
#pragma unroll
    for (int j = 0; j < 4; ++j) {
      const size_t roff = (crow0 + mf * 16 + j) * 4096 + ccol0;
      if (CM == 0) {
#pragma unroll
        for (int nf = 0; nf < 4; ++nf) C[roff + nf * 16] = acc[mf][nf][j];
      } else {
#pragma unroll
        for (int nf = 0; nf < 4; ++nf) Cb[roff + nf * 16] = f2bf(acc[mf][nf][j]);
      }
    }
}

// ---------------------------------------------------------------------------
// Kernel 4: y[row][:] = FHT_4096(C[row][:]) * SU * Wscale/4096.
// CM=1: read bf16 C from workspace; CM=0: in-place f32 on Y.
// ---------------------------------------------------------------------------
template <int CM>
__global__ __launch_bounds__(256) void rht_out_kernel(const unsigned short* __restrict__ Cb,
                                                      float* __restrict__ Y,
                                                      const float* __restrict__ SU,
                                                      const float* __restrict__ Wscale) {
  __shared__ float tmp[4096];
  const int row = blockIdx.x;
  const int t = threadIdx.x;
  const int lane = t & 63;
  const size_t base = (size_t)row * 4096;
  float v[16];
  if (CM == 0) {
    const float4* Y4 = (const float4*)(Y + base);
#pragma unroll
    for (int q = 0; q < 4; ++q) {
      float4 yv = Y4[t * 4 + q];
      v[q * 4 + 0] = yv.x; v[q * 4 + 1] = yv.y;
      v[q * 4 + 2] = yv.z; v[q * 4 + 3] = yv.w;
    }
  } else {
    const short8* Cp = (const short8*)(Cb + base + t * 16);
    union { short8 s; unsigned short u[8]; } lo, hi;
    lo.s = Cp[0]; hi.s = Cp[1];
#pragma unroll
    for (int j = 0; j < 8; ++j) { v[j] = bf2f(lo.u[j]); v[8 + j] = bf2f(hi.u[j]); }
  }
  FHT_BODY(v, tmp, t, lane)
  const float ws = Wscale[0] * (1.0f / 4096.0f);
  const float4* SU4 = (const float4*)SU;
  float4* Y4o = (float4*)(Y + base);
#pragma unroll
  for (int q = 0; q < 4; ++q) {
    float4 su = SU4[t * 4 + q];
    float4 o;
    o.x = v[q * 4 + 0] * su.x * ws;
    o.y = v[q * 4 + 1] * su.y * ws;
    o.z = v[q * 4 + 2] * su.z * ws;
    o.w = v[q * 4 + 3] * su.w * ws;
    Y4o[t * 4 + q] = o;
  }
}

// ---------------------------------------------------------------------------
extern "C" void kernel_launch(void* const* d_in, const int* in_sizes, int n_in,
                              void* d_out, int out_size, void* d_ws, size_t ws_size,
                              hipStream_t stream) {
  const float* x      = (const float*)d_in[0];
  const int*   Qidxs  = (const int*)d_in[1];
  const float* SU     = (const float*)d_in[2];
  const float* SV     = (const float*)d_in[3];
  const float* Wscale = (const float*)d_in[4];
  const float* cb     = (const float*)d_in[5];
  float* out = (float*)d_out;

  unsigned short* Arht = (unsigned short*)d_ws;                                      // 64 MB
  unsigned short* W    = (unsigned short*)((char*)d_ws + (size_t)64 * 1024 * 1024);  // 32 MB
  unsigned short* Cb   = (unsigned short*)((char*)d_ws + (size_t)96 * 1024 * 1024);  // 64 MB

  const bool bf16c = ws_size >= ((size_t)160 * 1024 * 1024);

  rht_in_kernel<<<8192, 256, 0, stream>>>(x, SV, Arht);
  decode_w_kernel<<<(4096 * 512) / 256, 256, 0, stream>>>(Qidxs, cb, W);
  if (bf16c) {
    gemm_bt_kernel<1><<<512, 512, 0, stream>>>(Arht, W, out, Cb);
    rht_out_kernel<1><<<8192, 256, 0, stream>>>(Cb, out, SU, Wscale);
  } else {
    gemm_bt_kernel<0><<<512, 512, 0, stream>>>(Arht, W, out, Cb);
    rht_out_kernel<0><<<8192, 256, 0, stream>>>(nullptr, out, SU, Wscale);
  }
}